// Round 6
// baseline (936.964 us; speedup 1.0000x reference)
//
#include <hip/hip_runtime.h>
#include <math.h>

#define N_ROWS   16384
#define K_EMB    8192
#define C_DIM    256
#define QUANT_N  4194304      // 16*256*32*32
#define QUANT_OFF 1
#define PERP_OFF  4194305
#define ENC_OFF   4194306

#define CAND_CAP 128

// ws layout in 4-byte units (same footprint as rounds 4-5)
#define WS_BK    0                          // 8192 f32
#define WS_AN    8192                       // 16384 f32
#define WS_AMIN  24576                      // 16384 u64
#define WS_CCNT  57344                      // 16384 u32
#define WS_CAND  73728                      // 16384*128 u64
#define WS_IDX   4268032                    // 16384 i32
#define WS_CNT   4284416                    // 8192 i32
#define WS_ACC   4292608                    // 1 double (+pad)
#define WS_XH    4292616                    // 16384*256 bf16
#define WS_EH    6389768                    // 8192*256 bf16

typedef __attribute__((ext_vector_type(8))) short short8_t;
typedef __attribute__((ext_vector_type(4))) float f32x4;
typedef __attribute__((ext_vector_type(8))) unsigned short u16x8;
typedef unsigned long long ull;

__device__ __forceinline__ unsigned short f2bf(float f) {
    unsigned int u = __float_as_uint(f);
    u += 0x7FFFu + ((u >> 16) & 1u);        // RNE (inputs are finite normals)
    return (unsigned short)(u >> 16);
}

// ---------------- init: replaces 3 small memsets ----------------
__global__ void vq_init_kernel(ull* __restrict__ amin, unsigned int* __restrict__ ccnt,
                               int* __restrict__ counts, double* __restrict__ acc) {
    int t = blockIdx.x * 256 + threadIdx.x;   // grid 64 -> 16384 threads
    amin[t] = 0xFFFFFFFFFFFFFFFFull;
    ccnt[t] = 0u;
    if (t < K_EMB) counts[t] = 0;
    if (t == 0) acc[0] = 0.0;
}

// ---------------- b_k = sum(emb[k,:]^2) (bitwise == rounds 1-5) ----------------
__global__ void vq_bk_kernel(const float* __restrict__ emb, float* __restrict__ bk) {
    int row  = blockIdx.x * 4 + (threadIdx.x >> 6);
    int lane = threadIdx.x & 63;
    float4 v = reinterpret_cast<const float4*>(emb)[(size_t)row * 64 + lane];
    float s = v.x * v.x + v.y * v.y + v.z * v.z + v.w * v.w;
#pragma unroll
    for (int o = 32; o > 0; o >>= 1) s += __shfl_down(s, o, 64);
    if (lane == 0) bk[row] = s;
}

// ---------------- a_n = sum(x_n^2), sequential ascending-c fmaf (== rounds 4-5) ----------------
__global__ void vq_an_kernel(const float* __restrict__ xin, float* __restrict__ an) {
    int n = blockIdx.x * 256 + threadIdx.x;
    int b = n >> 10, hw = n & 1023;
    const float* xr = xin + (size_t)b * (C_DIM * 1024) + hw;
    float s = 0.f;
    for (int c = 0; c < C_DIM; ++c) { float v = xr[(size_t)c * 1024]; s = fmaf(v, v, s); }
    an[n] = s;
}

// ---------------- pack x -> bf16 [n][c] row-major (transpose via LDS) ----------------
__global__ void vq_packx_kernel(const float* __restrict__ xin, unsigned short* __restrict__ xh) {
    __shared__ float tile[64][65];
    const int t = threadIdx.x;
    const int nb = blockIdx.x >> 2;
    const int cb = blockIdx.x & 3;
    const int n0 = nb * 64;
    const int b  = n0 >> 10, hw0 = n0 & 1023;
    {
        int cl = t >> 6, nl = t & 63;
#pragma unroll
        for (int i = 0; i < 16; ++i) {
            int c = cb * 64 + cl * 16 + i;
            tile[cl * 16 + i][nl] = xin[(size_t)b * (C_DIM * 1024) + (size_t)c * 1024 + hw0 + nl];
        }
    }
    __syncthreads();
    {
        int nl = t >> 2, cq = t & 3;
#pragma unroll
        for (int j = 0; j < 2; ++j) {
            u16x8 v;
#pragma unroll
            for (int jj = 0; jj < 8; ++jj) v[jj] = f2bf(tile[cq * 16 + j * 8 + jj][nl]);
            *reinterpret_cast<u16x8*>(&xh[(size_t)(n0 + nl) * 256 + cb * 64 + cq * 16 + j * 8]) = v;
        }
    }
}

// ---------------- pack emb -> bf16 [k][c] ----------------
__global__ void vq_packe_kernel(const float* __restrict__ emb, unsigned short* __restrict__ eh) {
    int flat = blockIdx.x * 256 + threadIdx.x;
    int k = flat >> 4, c16 = flat & 15;
    const float4* src = reinterpret_cast<const float4*>(emb) + (size_t)k * 64 + c16 * 4;
#pragma unroll
    for (int j = 0; j < 2; ++j) {
        float4 v0 = src[j * 2], v1 = src[j * 2 + 1];
        u16x8 v;
        v[0]=f2bf(v0.x); v[1]=f2bf(v0.y); v[2]=f2bf(v0.z); v[3]=f2bf(v0.w);
        v[4]=f2bf(v1.x); v[5]=f2bf(v1.y); v[6]=f2bf(v1.z); v[7]=f2bf(v1.w);
        *reinterpret_cast<u16x8*>(&eh[(size_t)k * 256 + c16 * 16 + j * 8]) = v;
    }
}

// ---------------- MFMA distance + approx-argmin + candidates + enc-zero ----------------
__launch_bounds__(256, 2)
__global__ void vq_mfma_kernel(const unsigned short* __restrict__ xh,
                               const unsigned short* __restrict__ eh,
                               const float* __restrict__ an,
                               const float* __restrict__ bk,
                               ull* __restrict__ amin,
                               unsigned int* __restrict__ ccnt,
                               ull* __restrict__ cand,
                               float* __restrict__ enc) {
    __shared__ unsigned short e_lds[256][72];
    __shared__ unsigned short x_lds[128][72];
    __shared__ ull key_lds[128][4];
    const int t  = threadIdx.x;
    const int rb = blockIdx.x >> 5;
    const int kb = blockIdx.x & 31;
    const int w  = t >> 6;
    const int l  = t & 63;
    const int lr = l & 15;
    const int lg = l >> 4;

    f32x4 acc[4][8];
#pragma unroll
    for (int kt = 0; kt < 4; ++kt)
#pragma unroll
        for (int rt = 0; rt < 8; ++rt) acc[kt][rt] = (f32x4){0.f, 0.f, 0.f, 0.f};

    const unsigned short* xbase = xh + (size_t)(rb * 128) * 256;
    const unsigned short* ebase = eh + (size_t)(kb * 256) * 256;
    // this block's 128 KB slice of encodings to zero (8B-aligned base)
    float2* enc_z = reinterpret_cast<float2*>(enc + (size_t)blockIdx.x * 32768);

    for (int cc = 0; cc < 4; ++cc) {
        __syncthreads();
#pragma unroll
        for (int i = 0; i < 8; ++i) {
            int flat = t + 256 * i;
            int kr = flat >> 3, u8 = flat & 7;
            *reinterpret_cast<u16x8*>(&e_lds[kr][u8 * 8]) =
                *reinterpret_cast<const u16x8*>(&ebase[(size_t)kr * 256 + cc * 64 + u8 * 8]);
        }
#pragma unroll
        for (int i = 0; i < 4; ++i) {
            int flat = t + 256 * i;
            int xr = flat >> 3, u8 = flat & 7;
            *reinterpret_cast<u16x8*>(&x_lds[xr][u8 * 8]) =
                *reinterpret_cast<const u16x8*>(&xbase[(size_t)xr * 256 + cc * 64 + u8 * 8]);
        }
        // streaming zero of enc slice: overlaps with MFMA phase, fire-and-forget
#pragma unroll
        for (int z = 0; z < 16; ++z)
            enc_z[(cc * 16 + z) * 256 + t] = (float2){0.f, 0.f};
        __syncthreads();
#pragma unroll
        for (int step = 0; step < 2; ++step) {
            const int cl = step * 32 + lg * 8;
            short8_t af[4], bf[8];
#pragma unroll
            for (int kt = 0; kt < 4; ++kt)
                af[kt] = *reinterpret_cast<const short8_t*>(&e_lds[w * 64 + kt * 16 + lr][cl]);
#pragma unroll
            for (int rt = 0; rt < 8; ++rt)
                bf[rt] = *reinterpret_cast<const short8_t*>(&x_lds[rt * 16 + lr][cl]);
#pragma unroll
            for (int kt = 0; kt < 4; ++kt)
#pragma unroll
                for (int rt = 0; rt < 8; ++rt)
                    acc[kt][rt] = __builtin_amdgcn_mfma_f32_16x16x32_bf16(af[kt], bf[rt], acc[kt][rt], 0, 0, 0);
        }
    }

    float bvals[16];
#pragma unroll
    for (int kt = 0; kt < 4; ++kt)
#pragma unroll
        for (int reg = 0; reg < 4; ++reg)
            bvals[kt * 4 + reg] = bk[kb * 256 + w * 64 + kt * 16 + lg * 4 + reg];

    // pass 1: d into acc (in place), per-wave per-row min -> LDS only
    float ar8[8];
#pragma unroll
    for (int rt = 0; rt < 8; ++rt) {
        const int row = rb * 128 + rt * 16 + lr;
        const float a_r = an[row];
        ar8[rt] = a_r;
        float mn = 3.402823466e38f; int mk = 0;
#pragma unroll
        for (int kt = 0; kt < 4; ++kt)
#pragma unroll
            for (int reg = 0; reg < 4; ++reg) {
                float d = fmaf(-2.f, acc[kt][rt][reg], a_r + bvals[kt * 4 + reg]);
                acc[kt][rt][reg] = d;
                int k = kb * 256 + w * 64 + kt * 16 + lg * 4 + reg;
                if (d < mn) { mn = d; mk = k; }
            }
        ull key = ((ull)__float_as_uint(mn) << 32) | (unsigned)mk;
        ull o1 = __shfl_xor(key, 16, 64); if (o1 < key) key = o1;
        ull o2 = __shfl_xor(key, 32, 64); if (o2 < key) key = o2;
        if (lg == 0) key_lds[rt * 16 + lr][w] = key;
    }
    __syncthreads();
    // pass 2: block-min -> ONE atomicMin per (block,row); candidates vs tight threshold
#pragma unroll
    for (int rt = 0; rt < 8; ++rt) {
        const int row = rb * 128 + rt * 16 + lr;
        ull bmin = key_lds[rt * 16 + lr][0];
#pragma unroll
        for (int j = 1; j < 4; ++j) { ull v = key_lds[rt * 16 + lr][j]; if (v < bmin) bmin = v; }
        if (w == 0 && lg == 0) atomicMin(&amin[row], bmin);
        ull obs = amin[row];              // racy: only ever >= final -> superset-safe
        if (obs < bmin) bmin = obs;
        float md  = __uint_as_float((unsigned)(bmin >> 32));
        float thr = md + fmaf(4.0e-5f, sqrtf(ar8[rt]), 1.6e-4f);   // 2*eps, 1.3x headroom
#pragma unroll
        for (int kt = 0; kt < 4; ++kt)
#pragma unroll
            for (int reg = 0; reg < 4; ++reg) {
                float d = acc[kt][rt][reg];
                if (d <= thr) {
                    int k = kb * 256 + w * 64 + kt * 16 + lg * 4 + reg;
                    unsigned pos = atomicAdd(&ccnt[row], 1u);
                    if (pos < CAND_CAP)
                        cand[(size_t)row * CAND_CAP + pos] =
                            ((ull)__float_as_uint(d) << 32) | (unsigned)k;
                }
            }
    }
}

// ---------------- exact re-check: one wave per row, coalesced x load ----------------
__global__ void vq_select_kernel(const float* __restrict__ xin,
                                 const float* __restrict__ emb,
                                 const float* __restrict__ an,
                                 const float* __restrict__ bk,
                                 const ull* __restrict__ amin,
                                 const unsigned int* __restrict__ ccnt,
                                 const ull* __restrict__ cand,
                                 int* __restrict__ idx_ws,
                                 int* __restrict__ counts,
                                 float* __restrict__ enc) {
    __shared__ float xrow4[256][4];
    const int t = threadIdx.x;
    const int w = t >> 6, l = t & 63;
    const int n0 = blockIdx.x * 4;          // 4 consecutive rows (same image)
    const int b  = n0 >> 10, hw0 = n0 & 1023;
    // cooperative load: thread t = channel c, one float4 covering the block's 4 hw
    {
        float4 v = *reinterpret_cast<const float4*>(
            xin + (size_t)b * (C_DIM * 1024) + (size_t)t * 1024 + hw0);
        xrow4[t][0] = v.x; xrow4[t][1] = v.y; xrow4[t][2] = v.z; xrow4[t][3] = v.w;
    }
    __syncthreads();

    const int r = n0 + w;
    const unsigned cnt = ccnt[r];
    const float a_r = an[r];
    const float glob = __uint_as_float((unsigned)(amin[r] >> 32));
    const float thr  = glob + fmaf(4.0e-5f, sqrtf(a_r), 1.6e-4f);

    ull mykey = 0xFFFFFFFFFFFFFFFFull;
    if (cnt <= CAND_CAP) {
        for (unsigned i = l; i < cnt; i += 64) {
            ull e64 = cand[(size_t)r * CAND_CAP + i];
            float dt = __uint_as_float((unsigned)(e64 >> 32));
            if (dt <= thr) {
                int k = (int)(unsigned)(e64 & 0xFFFFFFFFull);
                const float* e = emb + (size_t)k * C_DIM;
                float m = 0.f;
                for (int c = 0; c < C_DIM; ++c) m = fmaf(xrow4[c][w], e[c], m);
                float d = fmaf(-2.f, m, a_r + bk[k]);   // chain bitwise == rounds 4-5
                ull key = ((ull)__float_as_uint(d) << 32) | (unsigned)k;
                if (key < mykey) mykey = key;
            }
        }
    } else {
        // overflow fallback: wave-parallel exact full scan (rare, correct)
        for (int k = l; k < K_EMB; k += 64) {
            const float* e = emb + (size_t)k * C_DIM;
            float m = 0.f;
            for (int c = 0; c < C_DIM; ++c) m = fmaf(xrow4[c][w], e[c], m);
            float d = fmaf(-2.f, m, a_r + bk[k]);
            ull key = ((ull)__float_as_uint(d) << 32) | (unsigned)k;
            if (key < mykey) mykey = key;
        }
    }
#pragma unroll
    for (int o = 32; o > 0; o >>= 1) {
        ull ok = __shfl_xor(mykey, o, 64);
        if (ok < mykey) mykey = ok;
    }
    if (l == 0) {
        int bi = (int)(unsigned)(mykey & 0xFFFFFFFFull);
        idx_ws[r] = bi;
        atomicAdd(&counts[bi], 1);
        enc[(size_t)r * K_EMB + bi] = 1.0f;
    }
}

// ---------------- quantized output + loss reduction ----------------
__global__ void vq_quant_loss_kernel(const float* __restrict__ xin,
                                     const float* __restrict__ emb,
                                     const int* __restrict__ idx_ws,
                                     float* __restrict__ out,
                                     double* __restrict__ acc) {
    __shared__ float q_lds[64][257];
    __shared__ int   k_lds[64];
    const int tid = threadIdx.x;
    const int n0  = blockIdx.x * 64;
    const int b_img = n0 >> 10;
    const int hw0   = n0 & 1023;

    if (tid < 64) k_lds[tid] = idx_ws[n0 + tid];
    __syncthreads();
#pragma unroll
    for (int p = 0; p < 16; ++p) {
        int idx = tid + p * 256;
        int row = idx >> 6;
        int c4  = idx & 63;
        float4 q = reinterpret_cast<const float4*>(emb)[(size_t)k_lds[row] * 64 + c4];
        q_lds[row][c4 * 4 + 0] = q.x;
        q_lds[row][c4 * 4 + 1] = q.y;
        q_lds[row][c4 * 4 + 2] = q.z;
        q_lds[row][c4 * 4 + 3] = q.w;
    }
    __syncthreads();

    double local = 0.0;
    const size_t base = (size_t)b_img * (C_DIM * 1024) + hw0;
    const int hw = tid & 63;
    const int cb = tid >> 6;
    for (int pass = 0; pass < 64; ++pass) {
        int c = pass * 4 + cb;
        size_t off = base + (size_t)c * 1024 + hw;
        float x = xin[off];
        float q = q_lds[hw][c];
        float dq = q - x;
        out[QUANT_OFF + off] = x + dq;
        local += (double)dq * (double)dq;
    }
#pragma unroll
    for (int o = 32; o > 0; o >>= 1) local += __shfl_down(local, o, 64);
    __shared__ double wsum[4];
    if ((threadIdx.x & 63) == 0) wsum[threadIdx.x >> 6] = local;
    __syncthreads();
    if (threadIdx.x == 0) atomicAdd(acc, wsum[0] + wsum[1] + wsum[2] + wsum[3]);
}

// ---------------- perplexity + loss finalize ----------------
__global__ void vq_finalize_kernel(const int* __restrict__ counts,
                                   const double* __restrict__ acc,
                                   float* __restrict__ out) {
    double s = 0.0;
    for (int k = threadIdx.x; k < K_EMB; k += 256) {
        int c = counts[k];
        if (c > 0) {
            double p = (double)c * (1.0 / 16384.0);
            s += p * log(p + 1e-10);
        }
    }
#pragma unroll
    for (int o = 32; o > 0; o >>= 1) s += __shfl_down(s, o, 64);
    __shared__ double wsum[4];
    if ((threadIdx.x & 63) == 0) wsum[threadIdx.x >> 6] = s;
    __syncthreads();
    if (threadIdx.x == 0) {
        double tot = wsum[0] + wsum[1] + wsum[2] + wsum[3];
        out[PERP_OFF] = (float)exp(-tot);
        float l = (float)(acc[0] * (1.0 / (double)QUANT_N));
        out[0] = l + 0.25f * l;
    }
}

extern "C" void kernel_launch(void* const* d_in, const int* in_sizes, int n_in,
                              void* d_out, int out_size, void* d_ws, size_t ws_size,
                              hipStream_t stream) {
    const float* xin = (const float*)d_in[0];
    const float* emb = (const float*)d_in[1];
    float* out = (float*)d_out;
    float* ws  = (float*)d_ws;

    float*          bk     = ws + WS_BK;
    float*          an     = ws + WS_AN;
    ull*            amin   = (ull*)(ws + WS_AMIN);
    unsigned int*   ccnt   = (unsigned int*)(ws + WS_CCNT);
    ull*            cand   = (ull*)(ws + WS_CAND);
    int*            idx_ws = (int*)(ws + WS_IDX);
    int*            counts = (int*)(ws + WS_CNT);
    double*         acc    = (double*)(ws + WS_ACC);
    unsigned short* xh     = (unsigned short*)(ws + WS_XH);
    unsigned short* eh     = (unsigned short*)(ws + WS_EH);

    vq_init_kernel<<<64, 256, 0, stream>>>(amin, ccnt, counts, acc);
    vq_bk_kernel<<<K_EMB / 4, 256, 0, stream>>>(emb, bk);
    vq_an_kernel<<<N_ROWS / 256, 256, 0, stream>>>(xin, an);
    vq_packe_kernel<<<(K_EMB * 16) / 256, 256, 0, stream>>>(emb, eh);
    vq_packx_kernel<<<(N_ROWS / 64) * 4, 256, 0, stream>>>(xin, xh);
    vq_mfma_kernel<<<128 * 32, 256, 0, stream>>>(xh, eh, an, bk, amin, ccnt, cand, out + ENC_OFF);
    vq_select_kernel<<<N_ROWS / 4, 256, 0, stream>>>(xin, emb, an, bk, amin, ccnt, cand,
                                                     idx_ws, counts, out + ENC_OFF);
    vq_quant_loss_kernel<<<N_ROWS / 64, 256, 0, stream>>>(xin, emb, idx_ws, out, acc);
    vq_finalize_kernel<<<1, 256, 0, stream>>>(counts, acc, out);
}